// Round 4
// baseline (1003.616 us; speedup 1.0000x reference)
//
#include <hip/hip_runtime.h>

#define N_NODES 100000
#define N_EDGES 1600000
#define N_PAIRS 1000000
#define BSHIFT 7
#define BUCKET (1 << BSHIFT)                        // 128 nodes per bucket
#define NBUCKET ((N_NODES + BUCKET - 1) >> BSHIFT)  // 782
#define SC_THREADS 512
#define SC_K 32
#define SC_EPB (SC_THREADS * SC_K)                  // 16384 edges per block

// ---------------------------------------------------------------------------
// Bucket histogram: LDS-reduced per block, one global atomic per bucket.
// ---------------------------------------------------------------------------
__global__ void bhist_kernel(const int* __restrict__ dst, int* __restrict__ ghist) {
    __shared__ int hist[NBUCKET];
    int t = threadIdx.x;
    for (int i = t; i < NBUCKET; i += SC_THREADS) hist[i] = 0;
    __syncthreads();
    long long e0 = (long long)blockIdx.x * SC_EPB;
#pragma unroll
    for (int k = 0; k < SC_K; k++) {
        long long idx = e0 + (long long)k * SC_THREADS + t;
        if (idx < N_EDGES) atomicAdd(&hist[dst[idx] >> BSHIFT], 1);
    }
    __syncthreads();
    for (int i = t; i < NBUCKET; i += SC_THREADS)
        if (hist[i]) atomicAdd(&ghist[i], hist[i]);
}

// ---------------------------------------------------------------------------
// Exclusive scan of the 782 bucket counts (single block, Hillis-Steele).
// boff[NBUCKET] gets the total; bcursor seeded = boff.
// ---------------------------------------------------------------------------
__global__ void bscan_kernel(const int* __restrict__ ghist, int* __restrict__ boff,
                             int* __restrict__ bcursor) {
    __shared__ int tmp[1024];
    int t = threadIdx.x;
    tmp[t] = (t < NBUCKET) ? ghist[t] : 0;
    __syncthreads();
    for (int off = 1; off < 1024; off <<= 1) {
        int v = (t >= off) ? tmp[t - off] : 0;
        __syncthreads();
        tmp[t] += v;
        __syncthreads();
    }
    int excl = (t > 0) ? tmp[t - 1] : 0;
    if (t < NBUCKET) { boff[t] = excl; bcursor[t] = excl; }
    if (t == NBUCKET) boff[t] = excl;  // total == N_EDGES
}

// ---------------------------------------------------------------------------
// Bucket multisplit with REGISTER staging: each thread keeps its 32 packed
// edges in VGPRs between the count pass and the place pass. Packed entry:
// (src << 7) | (dst & 127)  — 24 bits. One bcursor atomic per (block,bucket).
// ---------------------------------------------------------------------------
__global__ void bscatter_kernel(const int* __restrict__ src,
                                const int* __restrict__ dst,
                                int* __restrict__ bcursor,
                                int* __restrict__ bedp) {
    __shared__ int hist[NBUCKET];
    __shared__ int base[NBUCKET];
    int t = threadIdx.x;
    for (int i = t; i < NBUCKET; i += SC_THREADS) hist[i] = 0;
    __syncthreads();
    long long e0 = (long long)blockIdx.x * SC_EPB;
    int pk[SC_K];
    int bk[SC_K];
#pragma unroll
    for (int k = 0; k < SC_K; k++) {
        long long idx = e0 + (long long)k * SC_THREADS + t;
        if (idx < N_EDGES) {
            int s = src[idx];
            int d = dst[idx];
            int b = d >> BSHIFT;
            pk[k] = (s << BSHIFT) | (d & (BUCKET - 1));
            bk[k] = b;
            atomicAdd(&hist[b], 1);
        } else {
            bk[k] = -1;
        }
    }
    __syncthreads();
    for (int i = t; i < NBUCKET; i += SC_THREADS) {
        int c = hist[i];
        base[i] = c ? atomicAdd(&bcursor[i], c) : 0;
        hist[i] = 0;  // reuse as rank counter
    }
    __syncthreads();
#pragma unroll
    for (int k = 0; k < SC_K; k++) {
        if (bk[k] >= 0) {
            int r = atomicAdd(&hist[bk[k]], 1);
            bedp[base[bk[k]] + r] = pk[k];
        }
    }
}

// ---------------------------------------------------------------------------
// Fused layer: one block per 128-node bucket.
// Phase 1: edge-parallel gather + LDS f32 atomic accumulation. Indices come
//   from one coalesced 32-wide load + shfl broadcast -> 32 independent row
//   gathers in flight per group. agg[n][c] bank = c: conflict-free ds_add.
// Phase 2: mean + dual matvec + bias (+ReLU) from LDS, write out rows.
// ---------------------------------------------------------------------------
template <bool RELU>
__global__ void fused_layer_kernel(const float* __restrict__ feat,
                                   const int* __restrict__ bedp,
                                   const int* __restrict__ boff,
                                   const float* __restrict__ Wl,
                                   const float* __restrict__ Wr,
                                   const float* __restrict__ b,
                                   float* __restrict__ out) {
    __shared__ float agg[BUCKET * 32];  // 16 KB
    __shared__ int cnt[BUCKET];
    __shared__ float sWl[1024], sWr[1024], sb[32];
    int t = threadIdx.x;
    for (int i = t; i < 1024; i += 256) {
        sWl[i] = Wl[i];
        sWr[i] = Wr[i];
    }
    if (t < 32) sb[t] = b[t];
    for (int i = t; i < BUCKET * 32; i += 256) agg[i] = 0.f;
    if (t < BUCKET) cnt[t] = 0;
    __syncthreads();

    int g = t >> 5;   // group 0..7
    int c = t & 31;   // channel
    int bkt = blockIdx.x;
    int ebeg = boff[bkt], eend = boff[bkt + 1];
    const float* fc = feat + c;

    // edge chunks of 32 per group, round-robin across 8 groups
    for (int j0 = ebeg + (g << 5); j0 < eend; j0 += (8 << 5)) {
        int m = eend - j0;
        if (m > 32) m = 32;
        int myp = (c < m) ? bedp[j0 + c] : 0;
        if (m == 32) {
#pragma unroll
            for (int k = 0; k < 32; k++) {
                int p = __shfl(myp, k, 32);
                float v = fc[(p >> BSHIFT) * 32];
                atomicAdd(&agg[(p & (BUCKET - 1)) * 32 + c], v);
                if (c == 0) atomicAdd(&cnt[p & (BUCKET - 1)], 1);
            }
        } else {
            for (int k = 0; k < m; k++) {
                int p = __shfl(myp, k, 32);
                float v = fc[(p >> BSHIFT) * 32];
                atomicAdd(&agg[(p & (BUCKET - 1)) * 32 + c], v);
                if (c == 0) atomicAdd(&cnt[p & (BUCKET - 1)], 1);
            }
        }
    }
    __syncthreads();

    // linear phase: 16 nodes per group
    int nbase = bkt << BSHIFT;
    for (int nl = g; nl < BUCKET; nl += 8) {
        int n = nbase + nl;
        if (n >= N_NODES) break;
        float inv = 1.0f / (float)max(cnt[nl], 1);
        float a = agg[nl * 32 + c] * inv;
        float xr = fc[n * 32];
        float o = sb[c];
#pragma unroll
        for (int i = 0; i < 32; i++) {
            float ai = __shfl(a, i, 32);
            float xi = __shfl(xr, i, 32);
            o += ai * sWl[i * 32 + c] + xi * sWr[i * 32 + c];
        }
        out[(long long)n * 32 + c] = RELU ? fmaxf(o, 0.f) : o;
    }
}

// ---------------------------------------------------------------------------
// Pair scoring: 4 consecutive pairs per 8-lane group. 2 int4 index loads,
// 8 independent row gathers, xor-reduce, lanes 0-3 store 4 contiguous floats
// (wave stores a full 128B contiguous segment of out).
// ---------------------------------------------------------------------------
__global__ void pair_kernel(const float* __restrict__ z,
                            const int* __restrict__ pairs,
                            float* __restrict__ out) {
    int gid = blockIdx.x * blockDim.x + threadIdx.x;
    int q = gid >> 3;  // quad of pairs
    int l = gid & 7;
    if (q >= N_PAIRS / 4) return;
    const int4* pp = (const int4*)pairs;
    int4 i01 = pp[2 * q];
    int4 i23 = pp[2 * q + 1];
    const float* zl = z + l * 4;
    float4 a0 = *(const float4*)(zl + (long long)i01.x * 32);
    float4 b0 = *(const float4*)(zl + (long long)i01.y * 32);
    float4 a1 = *(const float4*)(zl + (long long)i01.z * 32);
    float4 b1 = *(const float4*)(zl + (long long)i01.w * 32);
    float4 a2 = *(const float4*)(zl + (long long)i23.x * 32);
    float4 b2 = *(const float4*)(zl + (long long)i23.y * 32);
    float4 a3 = *(const float4*)(zl + (long long)i23.z * 32);
    float4 b3 = *(const float4*)(zl + (long long)i23.w * 32);
    float d0 = a0.x * b0.x + a0.y * b0.y + a0.z * b0.z + a0.w * b0.w;
    float d1 = a1.x * b1.x + a1.y * b1.y + a1.z * b1.z + a1.w * b1.w;
    float d2 = a2.x * b2.x + a2.y * b2.y + a2.z * b2.z + a2.w * b2.w;
    float d3 = a3.x * b3.x + a3.y * b3.y + a3.z * b3.z + a3.w * b3.w;
#pragma unroll
    for (int off = 4; off >= 1; off >>= 1) {
        d0 += __shfl_xor(d0, off, 8);
        d1 += __shfl_xor(d1, off, 8);
        d2 += __shfl_xor(d2, off, 8);
        d3 += __shfl_xor(d3, off, 8);
    }
    if (l < 4) {
        float v = (l == 0) ? d0 : (l == 1) ? d1 : (l == 2) ? d2 : d3;
        out[4 * q + l] = v;
    }
}

// ---------------------------------------------------------------------------
extern "C" void kernel_launch(void* const* d_in, const int* in_sizes, int n_in,
                              void* d_out, int out_size, void* d_ws, size_t ws_size,
                              hipStream_t stream) {
    const float* x   = (const float*)d_in[0];
    const int*   ei  = (const int*)d_in[1];   // [2, E] row-major
    const int*   prs = (const int*)d_in[2];   // [P, 2] row-major
    const float* Wl1 = (const float*)d_in[3];
    const float* Wr1 = (const float*)d_in[4];
    const float* b1  = (const float*)d_in[5];
    const float* Wl2 = (const float*)d_in[6];
    const float* Wr2 = (const float*)d_in[7];
    const float* b2  = (const float*)d_in[8];
    float* out = (float*)d_out;

    const int* src = ei;
    const int* dst = ei + N_EDGES;

    // ws: h [N*32 f] | z [N*32 f] | bedp [E i] | ghist [782] | boff [783] | bcursor [782]
    float* h = (float*)d_ws;
    float* z = h + (size_t)N_NODES * 32;
    int* bedp    = (int*)(z + (size_t)N_NODES * 32);
    int* ghist   = bedp + N_EDGES;
    int* boff    = ghist + NBUCKET;
    int* bcursor = boff + (NBUCKET + 1);

    int sc_blocks = (N_EDGES + SC_EPB - 1) / SC_EPB;  // 98
    int pair_blocks = (int)(((long long)N_PAIRS * 2 + 255) / 256);  // 2M threads

    // ---- bucket-sorted edge list (once, shared by both layers) ----
    hipMemsetAsync(ghist, 0, sizeof(int) * NBUCKET, stream);
    bhist_kernel<<<sc_blocks, SC_THREADS, 0, stream>>>(dst, ghist);
    bscan_kernel<<<1, 1024, 0, stream>>>(ghist, boff, bcursor);
    bscatter_kernel<<<sc_blocks, SC_THREADS, 0, stream>>>(src, dst, bcursor, bedp);

    // ---- layer 1: x -> h ----
    fused_layer_kernel<true><<<NBUCKET, 256, 0, stream>>>(x, bedp, boff, Wl1, Wr1, b1, h);
    // ---- layer 2: h -> z ----
    fused_layer_kernel<false><<<NBUCKET, 256, 0, stream>>>(h, bedp, boff, Wl2, Wr2, b2, z);

    // ---- pair scoring ----
    pair_kernel<<<pair_blocks, 256, 0, stream>>>(z, prs, out);
}

// Round 5
// 469.461 us; speedup vs baseline: 2.1378x; 2.1378x over previous
//
#include <hip/hip_runtime.h>

#define N_NODES 100000
#define N_EDGES 1600000
#define N_PAIRS 1000000
#define SCAN_CHUNK 1024
#define NB_SCAN ((N_NODES + SCAN_CHUNK - 1) / SCAN_CHUNK)  // 98
#define BSHIFT 10
#define NBUCKET ((N_NODES + (1 << BSHIFT) - 1) >> BSHIFT)  // 98 buckets of 1024 nodes
#define EPB 2048  // edges per block in bscatter

// ---------------------------------------------------------------------------
// CSR build step 1: in-degree histogram (int atomics).
// ---------------------------------------------------------------------------
__global__ void degree_kernel(const int* __restrict__ dst, int* __restrict__ deg) {
    int e = blockIdx.x * blockDim.x + threadIdx.x;
    if (e < N_EDGES) atomicAdd(&deg[dst[e]], 1);
}

// ---------------------------------------------------------------------------
// CSR build step 2a: per-block inclusive scan of deg (1024 elems/block).
// ---------------------------------------------------------------------------
__global__ void scan1_kernel(const int* __restrict__ deg,
                             int* __restrict__ incl,
                             int* __restrict__ bsum) {
    __shared__ int part[256];
    int t = threadIdx.x;
    int idx = blockIdx.x * SCAN_CHUNK + t * 4;
    int4 v = make_int4(0, 0, 0, 0);
    if (idx + 3 < N_NODES) {
        v = *(const int4*)(deg + idx);
    } else {
        if (idx + 0 < N_NODES) v.x = deg[idx + 0];
        if (idx + 1 < N_NODES) v.y = deg[idx + 1];
        if (idx + 2 < N_NODES) v.z = deg[idx + 2];
        if (idx + 3 < N_NODES) v.w = deg[idx + 3];
    }
    int s0 = v.x, s1 = s0 + v.y, s2 = s1 + v.z, s3 = s2 + v.w;
    part[t] = s3;
    __syncthreads();
    for (int off = 1; off < 256; off <<= 1) {
        int val = (t >= off) ? part[t - off] : 0;
        __syncthreads();
        part[t] += val;
        __syncthreads();
    }
    int excl = (t > 0) ? part[t - 1] : 0;
    if (idx + 0 < N_NODES) incl[idx + 0] = excl + s0;
    if (idx + 1 < N_NODES) incl[idx + 1] = excl + s1;
    if (idx + 2 < N_NODES) incl[idx + 2] = excl + s2;
    if (idx + 3 < N_NODES) incl[idx + 3] = excl + s3;
    if (t == 255) bsum[blockIdx.x] = part[255];
}

// ---------------------------------------------------------------------------
// CSR build step 2b: exclusive scan of the 98 block sums (serial, tiny).
// ---------------------------------------------------------------------------
__global__ void scan2_kernel(int* __restrict__ bsum, int* __restrict__ offsets) {
    if (threadIdx.x == 0 && blockIdx.x == 0) {
        int run = 0;
        for (int i = 0; i < NB_SCAN; i++) {
            int t = bsum[i];
            bsum[i] = run;
            run += t;
        }
        offsets[N_NODES] = run;  // == N_EDGES
    }
}

// ---------------------------------------------------------------------------
// CSR build step 2c: finalize exclusive offsets; seed per-bucket cursors.
// ---------------------------------------------------------------------------
__global__ void scan3_kernel(const int* __restrict__ incl,
                             const int* __restrict__ deg,
                             const int* __restrict__ bsum,
                             int* __restrict__ offsets,
                             int* __restrict__ bcursor) {
    int i = blockIdx.x * blockDim.x + threadIdx.x;
    if (i < N_NODES) {
        int off = incl[i] - deg[i] + bsum[i / SCAN_CHUNK];
        offsets[i] = off;
        if ((i & ((1 << BSHIFT) - 1)) == 0) bcursor[i >> BSHIFT] = off;
    }
}

// ---------------------------------------------------------------------------
// CSR build step 3a: bucket-level multisplit (1024-node buckets). LDS-staged,
// one global cursor atomic per (block,bucket), contiguous int2 run writes.
// ---------------------------------------------------------------------------
__global__ void bscatter_kernel(const int* __restrict__ src,
                                const int* __restrict__ dst,
                                int* __restrict__ bcursor,
                                int2* __restrict__ bed) {
    __shared__ int hist[NBUCKET];
    __shared__ int base[NBUCKET];
    __shared__ int2 stage[EPB];  // 16 KB
    int t = threadIdx.x;
    long long e0 = (long long)blockIdx.x * EPB;
    int cnt = (int)((N_EDGES - e0 < EPB) ? (N_EDGES - e0) : EPB);

    for (int i = t; i < NBUCKET; i += blockDim.x) hist[i] = 0;
    __syncthreads();
    for (int i = t; i < cnt; i += blockDim.x) {
        int s = src[e0 + i];
        int d = dst[e0 + i];
        stage[i] = make_int2(s, d);
        atomicAdd(&hist[d >> BSHIFT], 1);
    }
    __syncthreads();
    for (int i = t; i < NBUCKET; i += blockDim.x) {
        int c = hist[i];
        base[i] = c ? atomicAdd(&bcursor[i], c) : 0;
        hist[i] = 0;  // reuse as rank counter
    }
    __syncthreads();
    for (int i = t; i < cnt; i += blockDim.x) {
        int2 sd = stage[i];
        int b = sd.y >> BSHIFT;
        int r = atomicAdd(&hist[b], 1);
        bed[base[b] + r] = sd;
    }
}

// ---------------------------------------------------------------------------
// CSR build step 3b: fine scatter within each bucket; per-node cursors in LDS,
// csr writes confined to the bucket's contiguous ~65KB region.
// ---------------------------------------------------------------------------
__global__ void ffill_kernel(const int2* __restrict__ bed,
                             const int* __restrict__ offs,
                             int* __restrict__ csr) {
    __shared__ int cur[1 << BSHIFT];
    int b = blockIdx.x;
    int nbase = b << BSHIFT;
    int t = threadIdx.x;
    for (int i = t; i < (1 << BSHIFT); i += blockDim.x) {
        int n = nbase + i;
        cur[i] = (n < N_NODES) ? offs[n] : 0;
    }
    __syncthreads();
    int nend = nbase + (1 << BSHIFT);
    if (nend > N_NODES) nend = N_NODES;
    int beg = offs[nbase];
    int end = offs[nend];
    for (int i = beg + t; i < end; i += blockDim.x) {
        int2 sd = bed[i];
        int pos = atomicAdd(&cur[sd.y & ((1 << BSHIFT) - 1)], 1);
        csr[pos] = sd.x;
    }
}

// ---------------------------------------------------------------------------
// Fused pull-aggregate + mean + dual matvec + bias (+ReLU).
// One node per 32-lane group; LANE j GATHERS NEIGHBOR j's FULL ROW
// (8 independent float4 loads) -> up to 256 loads in flight per group.
// 5-stage shfl_xor butterfly all-reduces the 32-float partial rows so every
// lane holds the complete aggregate; matvec then reads registers directly
// (no acc broadcast). All register indices compile-time (no scratch).
// ---------------------------------------------------------------------------
template <bool RELU>
__global__ void agg_linear_kernel(const float* __restrict__ feat,
                                  const int* __restrict__ csr,
                                  const int* __restrict__ offs,
                                  const float* __restrict__ Wl,
                                  const float* __restrict__ Wr,
                                  const float* __restrict__ b,
                                  float* __restrict__ out) {
    __shared__ float sWl[1024], sWr[1024], sb[32];
    for (int i = threadIdx.x; i < 1024; i += blockDim.x) {
        sWl[i] = Wl[i];
        sWr[i] = Wr[i];
    }
    if (threadIdx.x < 32) sb[threadIdx.x] = b[threadIdx.x];
    __syncthreads();

    int g = threadIdx.x >> 5;   // group 0..7
    int c = threadIdx.x & 31;   // lane within group (= channel in matvec)
    int n = blockIdx.x * 8 + g;
    if (n >= N_NODES) return;

    int beg = offs[n], end = offs[n + 1];
    int deg = end - beg;

    float4 acc[8];
#pragma unroll
    for (int q = 0; q < 8; q++) acc[q] = make_float4(0.f, 0.f, 0.f, 0.f);

    // lane c handles neighbors beg+c, beg+c+32, ... : full-row float4 loads.
    for (int j = beg + c; j < end; j += 32) {
        int s = csr[j];  // coalesced across lanes
        const float4* rp = (const float4*)(feat + (long long)s * 32);
#pragma unroll
        for (int q = 0; q < 8; q++) {
            float4 v = rp[q];
            acc[q].x += v.x; acc[q].y += v.y; acc[q].z += v.z; acc[q].w += v.w;
        }
    }

    // butterfly all-reduce across the 32 lanes (each float4 component).
#pragma unroll
    for (int m = 1; m < 32; m <<= 1) {
#pragma unroll
        for (int q = 0; q < 8; q++) {
            acc[q].x += __shfl_xor(acc[q].x, m, 32);
            acc[q].y += __shfl_xor(acc[q].y, m, 32);
            acc[q].z += __shfl_xor(acc[q].z, m, 32);
            acc[q].w += __shfl_xor(acc[q].w, m, 32);
        }
    }

    float inv = 1.0f / (float)max(deg, 1);
#pragma unroll
    for (int q = 0; q < 8; q++) {
        acc[q].x *= inv; acc[q].y *= inv; acc[q].z *= inv; acc[q].w *= inv;
    }

    float xr = feat[(long long)n * 32 + c];  // root feature, channel c
    float o = sb[c];
#pragma unroll
    for (int q = 0; q < 8; q++) {
        int i0 = q * 4;
        float xi;
        xi = __shfl(xr, i0 + 0, 32);
        o += acc[q].x * sWl[(i0 + 0) * 32 + c] + xi * sWr[(i0 + 0) * 32 + c];
        xi = __shfl(xr, i0 + 1, 32);
        o += acc[q].y * sWl[(i0 + 1) * 32 + c] + xi * sWr[(i0 + 1) * 32 + c];
        xi = __shfl(xr, i0 + 2, 32);
        o += acc[q].z * sWl[(i0 + 2) * 32 + c] + xi * sWr[(i0 + 2) * 32 + c];
        xi = __shfl(xr, i0 + 3, 32);
        o += acc[q].w * sWl[(i0 + 3) * 32 + c] + xi * sWr[(i0 + 3) * 32 + c];
    }
    out[(long long)n * 32 + c] = RELU ? fmaxf(o, 0.f) : o;
}

// ---------------------------------------------------------------------------
// Pair scoring: 4 consecutive pairs per 8-lane group; 8 independent row
// gathers in flight; contiguous 16B store per 8-lane group.
// ---------------------------------------------------------------------------
__global__ void pair_kernel(const float* __restrict__ z,
                            const int* __restrict__ pairs,
                            float* __restrict__ out) {
    int gid = blockIdx.x * blockDim.x + threadIdx.x;
    int q = gid >> 3;  // quad of pairs
    int l = gid & 7;
    if (q >= N_PAIRS / 4) return;
    const int4* pp = (const int4*)pairs;
    int4 i01 = pp[2 * q];
    int4 i23 = pp[2 * q + 1];
    const float* zl = z + l * 4;
    float4 a0 = *(const float4*)(zl + (long long)i01.x * 32);
    float4 b0 = *(const float4*)(zl + (long long)i01.y * 32);
    float4 a1 = *(const float4*)(zl + (long long)i01.z * 32);
    float4 b1 = *(const float4*)(zl + (long long)i01.w * 32);
    float4 a2 = *(const float4*)(zl + (long long)i23.x * 32);
    float4 b2 = *(const float4*)(zl + (long long)i23.y * 32);
    float4 a3 = *(const float4*)(zl + (long long)i23.z * 32);
    float4 b3 = *(const float4*)(zl + (long long)i23.w * 32);
    float d0 = a0.x * b0.x + a0.y * b0.y + a0.z * b0.z + a0.w * b0.w;
    float d1 = a1.x * b1.x + a1.y * b1.y + a1.z * b1.z + a1.w * b1.w;
    float d2 = a2.x * b2.x + a2.y * b2.y + a2.z * b2.z + a2.w * b2.w;
    float d3 = a3.x * b3.x + a3.y * b3.y + a3.z * b3.z + a3.w * b3.w;
#pragma unroll
    for (int off = 4; off >= 1; off >>= 1) {
        d0 += __shfl_xor(d0, off, 8);
        d1 += __shfl_xor(d1, off, 8);
        d2 += __shfl_xor(d2, off, 8);
        d3 += __shfl_xor(d3, off, 8);
    }
    if (l < 4) {
        float v = (l == 0) ? d0 : (l == 1) ? d1 : (l == 2) ? d2 : d3;
        out[4 * q + l] = v;
    }
}

// ---------------------------------------------------------------------------
extern "C" void kernel_launch(void* const* d_in, const int* in_sizes, int n_in,
                              void* d_out, int out_size, void* d_ws, size_t ws_size,
                              hipStream_t stream) {
    const float* x   = (const float*)d_in[0];
    const int*   ei  = (const int*)d_in[1];   // [2, E] row-major
    const int*   prs = (const int*)d_in[2];   // [P, 2] row-major
    const float* Wl1 = (const float*)d_in[3];
    const float* Wr1 = (const float*)d_in[4];
    const float* b1  = (const float*)d_in[5];
    const float* Wl2 = (const float*)d_in[6];
    const float* Wr2 = (const float*)d_in[7];
    const float* b2  = (const float*)d_in[8];
    float* out = (float*)d_out;

    const int* src = ei;
    const int* dst = ei + N_EDGES;

    // ws: h [N*32 f] | z [N*32 f] | csr [E i] | deg [N i] | incl [N i]
    //     | offsets [N+1 i] | bsum [128 i] | bcursor [128 i]
    // bed (int2, E) aliases z: z is only written in layer 2, after the CSR
    // build has fully consumed bed.
    float* h = (float*)d_ws;
    float* z = h + (size_t)N_NODES * 32;
    int* csr     = (int*)(z + (size_t)N_NODES * 32);
    int* deg     = csr + N_EDGES;
    int* incl    = deg + N_NODES;
    int* offsets = incl + N_NODES;
    int* bsum    = offsets + (N_NODES + 1);
    int* bcursor = bsum + 128;
    int2* bed    = (int2*)z;

    const int BT = 256;
    int edge_blocks = (N_EDGES + BT - 1) / BT;
    int node_blocks = (N_NODES + BT - 1) / BT;
    int bsc_blocks  = (N_EDGES + EPB - 1) / EPB;
    int agg_blocks  = (N_NODES + 7) / 8;
    int pair_blocks = (int)(((long long)N_PAIRS * 2 + 255) / 256);

    // ---- CSR build (once, shared by both layers) ----
    hipMemsetAsync(deg, 0, sizeof(int) * N_NODES, stream);
    degree_kernel<<<edge_blocks, BT, 0, stream>>>(dst, deg);
    scan1_kernel<<<NB_SCAN, BT, 0, stream>>>(deg, incl, bsum);
    scan2_kernel<<<1, 64, 0, stream>>>(bsum, offsets);
    scan3_kernel<<<node_blocks, BT, 0, stream>>>(incl, deg, bsum, offsets, bcursor);
    bscatter_kernel<<<bsc_blocks, BT, 0, stream>>>(src, dst, bcursor, bed);
    ffill_kernel<<<NBUCKET, 512, 0, stream>>>(bed, offsets, csr);

    // ---- layer 1: x -> h ----
    agg_linear_kernel<true><<<agg_blocks, BT, 0, stream>>>(x, csr, offsets, Wl1, Wr1, b1, h);
    // ---- layer 2: h -> z ----  (z overwrites bed, which is now dead)
    agg_linear_kernel<false><<<agg_blocks, BT, 0, stream>>>(h, csr, offsets, Wl2, Wr2, b2, z);

    // ---- pair scoring ----
    pair_kernel<<<pair_blocks, BT, 0, stream>>>(z, prs, out);
}

// Round 6
// 360.027 us; speedup vs baseline: 2.7876x; 1.3040x over previous
//
#include <hip/hip_runtime.h>

typedef unsigned short ushort_t;

#define N_NODES 100000
#define N_EDGES 1600000
#define N_PAIRS 1000000
#define SCAN_CHUNK 1024
#define NB_SCAN ((N_NODES + SCAN_CHUNK - 1) / SCAN_CHUNK)  // 98
#define BSHIFT 9
#define BUCKET (1 << BSHIFT)                               // 512-node buckets
#define NBUCKET ((N_NODES + BUCKET - 1) >> BSHIFT)         // 196
#define SC_T 512
#define SC_K 8
#define EPB (SC_T * SC_K)                                  // 4096 edges/block

// ---- bf16 helpers (RNE) ----------------------------------------------------
__device__ __forceinline__ float bf2f(ushort_t u) {
    return __uint_as_float(((unsigned)u) << 16);
}
__device__ __forceinline__ ushort_t f2bf(float f) {
    unsigned u = __float_as_uint(f);
    return (ushort_t)((u + 0x7FFFu + ((u >> 16) & 1u)) >> 16);
}

// ---------------------------------------------------------------------------
// Convert f32 feature table -> bf16 table (vectorized, 19 MB traffic).
// ---------------------------------------------------------------------------
__global__ void cvt_kernel(const float* __restrict__ in, ushort_t* __restrict__ out) {
    int i = blockIdx.x * blockDim.x + threadIdx.x;  // over N*32/4
    if (i < N_NODES * 8) {
        float4 v = ((const float4*)in)[i];
        ushort4 o;
        o.x = f2bf(v.x); o.y = f2bf(v.y); o.z = f2bf(v.z); o.w = f2bf(v.w);
        ((ushort4*)out)[i] = o;
    }
}

// ---------------------------------------------------------------------------
// CSR build step 1: in-degree histogram (int atomics).
// ---------------------------------------------------------------------------
__global__ void degree_kernel(const int* __restrict__ dst, int* __restrict__ deg) {
    int e = blockIdx.x * blockDim.x + threadIdx.x;
    if (e < N_EDGES) atomicAdd(&deg[dst[e]], 1);
}

// ---------------------------------------------------------------------------
// CSR build step 2a: per-block inclusive scan of deg (1024 elems/block).
// ---------------------------------------------------------------------------
__global__ void scan1_kernel(const int* __restrict__ deg,
                             int* __restrict__ incl,
                             int* __restrict__ bsum) {
    __shared__ int part[256];
    int t = threadIdx.x;
    int idx = blockIdx.x * SCAN_CHUNK + t * 4;
    int4 v = make_int4(0, 0, 0, 0);
    if (idx + 3 < N_NODES) {
        v = *(const int4*)(deg + idx);
    } else {
        if (idx + 0 < N_NODES) v.x = deg[idx + 0];
        if (idx + 1 < N_NODES) v.y = deg[idx + 1];
        if (idx + 2 < N_NODES) v.z = deg[idx + 2];
        if (idx + 3 < N_NODES) v.w = deg[idx + 3];
    }
    int s0 = v.x, s1 = s0 + v.y, s2 = s1 + v.z, s3 = s2 + v.w;
    part[t] = s3;
    __syncthreads();
    for (int off = 1; off < 256; off <<= 1) {
        int val = (t >= off) ? part[t - off] : 0;
        __syncthreads();
        part[t] += val;
        __syncthreads();
    }
    int excl = (t > 0) ? part[t - 1] : 0;
    if (idx + 0 < N_NODES) incl[idx + 0] = excl + s0;
    if (idx + 1 < N_NODES) incl[idx + 1] = excl + s1;
    if (idx + 2 < N_NODES) incl[idx + 2] = excl + s2;
    if (idx + 3 < N_NODES) incl[idx + 3] = excl + s3;
    if (t == 255) bsum[blockIdx.x] = part[255];
}

// ---------------------------------------------------------------------------
// CSR build step 2b: exclusive scan of the 98 block sums (serial, tiny).
// ---------------------------------------------------------------------------
__global__ void scan2_kernel(int* __restrict__ bsum, int* __restrict__ offsets) {
    if (threadIdx.x == 0 && blockIdx.x == 0) {
        int run = 0;
        for (int i = 0; i < NB_SCAN; i++) {
            int t = bsum[i];
            bsum[i] = run;
            run += t;
        }
        offsets[N_NODES] = run;  // == N_EDGES
    }
}

// ---------------------------------------------------------------------------
// CSR build step 2c: finalize exclusive offsets; seed per-bucket cursors.
// ---------------------------------------------------------------------------
__global__ void scan3_kernel(const int* __restrict__ incl,
                             const int* __restrict__ deg,
                             const int* __restrict__ bsum,
                             int* __restrict__ offsets,
                             int* __restrict__ bcursor) {
    int i = blockIdx.x * blockDim.x + threadIdx.x;
    if (i < N_NODES) {
        int off = incl[i] - deg[i] + bsum[i / SCAN_CHUNK];
        offsets[i] = off;
        if ((i & (BUCKET - 1)) == 0) bcursor[i >> BSHIFT] = off;
    }
}

// ---------------------------------------------------------------------------
// CSR build 3a: bucket multisplit, PACKED 4B entries (src<<9 | dst_local).
// LDS-staged; one global cursor atomic per (block,bucket); contiguous runs.
// ---------------------------------------------------------------------------
__global__ void bscatter_kernel(const int* __restrict__ src,
                                const int* __restrict__ dst,
                                int* __restrict__ bcursor,
                                int* __restrict__ bed) {
    __shared__ int hist[NBUCKET];
    __shared__ int base[NBUCKET];
    __shared__ int stage[EPB];            // 16 KB
    __shared__ unsigned char sbkt[EPB];   // 4 KB
    int t = threadIdx.x;
    long long e0 = (long long)blockIdx.x * EPB;
    int cnt = (int)((N_EDGES - e0 < EPB) ? (N_EDGES - e0) : EPB);

    for (int i = t; i < NBUCKET; i += SC_T) hist[i] = 0;
    __syncthreads();
    for (int i = t; i < cnt; i += SC_T) {
        int s = src[e0 + i];
        int d = dst[e0 + i];
        int b = d >> BSHIFT;
        stage[i] = (s << BSHIFT) | (d & (BUCKET - 1));  // src<2^17 -> fits 26 bits
        sbkt[i] = (unsigned char)b;                      // NBUCKET=196 <= 255
        atomicAdd(&hist[b], 1);
    }
    __syncthreads();
    for (int i = t; i < NBUCKET; i += SC_T) {
        int c = hist[i];
        base[i] = c ? atomicAdd(&bcursor[i], c) : 0;
        hist[i] = 0;  // reuse as rank counter
    }
    __syncthreads();
    for (int i = t; i < cnt; i += SC_T) {
        int b = sbkt[i];
        int r = atomicAdd(&hist[b], 1);
        bed[base[b] + r] = stage[i];
    }
}

// ---------------------------------------------------------------------------
// CSR build 3b: fine scatter per bucket; per-node cursors in LDS; csr writes
// confined to the bucket's contiguous ~32KB region.
// ---------------------------------------------------------------------------
__global__ void ffill_kernel(const int* __restrict__ bed,
                             const int* __restrict__ offs,
                             int* __restrict__ csr) {
    __shared__ int cur[BUCKET];
    int b = blockIdx.x;
    int nbase = b << BSHIFT;
    int t = threadIdx.x;
    for (int i = t; i < BUCKET; i += blockDim.x) {
        int n = nbase + i;
        cur[i] = (n < N_NODES) ? offs[n] : 0;
    }
    __syncthreads();
    int nend = nbase + BUCKET;
    if (nend > N_NODES) nend = N_NODES;
    int beg = offs[nbase];
    int end = offs[nend];
    for (int i = beg + t; i < end; i += blockDim.x) {
        int p = bed[i];
        int pos = atomicAdd(&cur[p & (BUCKET - 1)], 1);
        csr[pos] = p >> BSHIFT;
    }
}

// ---------------------------------------------------------------------------
// Fused pull-aggregate + mean + dual matvec + bias (+ReLU), bf16 gathers.
// Round-3 structure (best measured): lane=channel, 8 groups/block, 8-way
// edge unroll -> 8 coalesced 64B row-gathers in flight per group.
// ROOT16: root feature from bf16 table (layer 2) vs f32 input (layer 1).
// Output written as bf16 only.
// ---------------------------------------------------------------------------
template <bool RELU, bool ROOT16>
__global__ void agg_linear_kernel(const ushort_t* __restrict__ feat16,
                                  const float* __restrict__ feat32,
                                  const int* __restrict__ csr,
                                  const int* __restrict__ offs,
                                  const float* __restrict__ Wl,
                                  const float* __restrict__ Wr,
                                  const float* __restrict__ b,
                                  ushort_t* __restrict__ out16) {
    __shared__ float sWl[1024], sWr[1024], sb[32];
    for (int i = threadIdx.x; i < 1024; i += blockDim.x) {
        sWl[i] = Wl[i];
        sWr[i] = Wr[i];
    }
    if (threadIdx.x < 32) sb[threadIdx.x] = b[threadIdx.x];
    __syncthreads();

    int g = threadIdx.x >> 5;
    int c = threadIdx.x & 31;
    int n = blockIdx.x * 8 + g;
    if (n >= N_NODES) return;

    const ushort_t* fc = feat16 + c;
    int beg = offs[n], end = offs[n + 1];
    float a0 = 0.f, a1 = 0.f, a2 = 0.f, a3 = 0.f;
    float a4 = 0.f, a5 = 0.f, a6 = 0.f, a7 = 0.f;
    int j = beg;
    for (; j + 7 < end; j += 8) {
        int s0 = csr[j + 0], s1 = csr[j + 1], s2 = csr[j + 2], s3 = csr[j + 3];
        int s4 = csr[j + 4], s5 = csr[j + 5], s6 = csr[j + 6], s7 = csr[j + 7];
        a0 += bf2f(fc[s0 * 32]); a1 += bf2f(fc[s1 * 32]);
        a2 += bf2f(fc[s2 * 32]); a3 += bf2f(fc[s3 * 32]);
        a4 += bf2f(fc[s4 * 32]); a5 += bf2f(fc[s5 * 32]);
        a6 += bf2f(fc[s6 * 32]); a7 += bf2f(fc[s7 * 32]);
    }
    for (; j < end; j++) a0 += bf2f(fc[csr[j] * 32]);
    float inv = 1.0f / (float)max(end - beg, 1);
    float acc = (((a0 + a1) + (a2 + a3)) + ((a4 + a5) + (a6 + a7))) * inv;
    float xr = ROOT16 ? bf2f(fc[n * 32]) : feat32[(long long)n * 32 + c];

    float o = sb[c];
#pragma unroll
    for (int i = 0; i < 32; i++) {
        float ai = __shfl(acc, i, 32);
        float xi = __shfl(xr, i, 32);
        o += ai * sWl[i * 32 + c] + xi * sWr[i * 32 + c];
    }
    float r = RELU ? fmaxf(o, 0.f) : o;
    out16[(long long)n * 32 + c] = f2bf(r);
}

// ---------------------------------------------------------------------------
// Pair scoring from bf16 z: 4 consecutive pairs per 8-lane group; each lane
// reads ushort4 (8B) per endpoint row (8 lanes cover the 64B row); 8
// independent gathers in flight; contiguous 16B store per group.
// ---------------------------------------------------------------------------
__global__ void pair_kernel(const ushort_t* __restrict__ z16,
                            const int* __restrict__ pairs,
                            float* __restrict__ out) {
    int gid = blockIdx.x * blockDim.x + threadIdx.x;
    int q = gid >> 3;
    int l = gid & 7;
    if (q >= N_PAIRS / 4) return;
    const int4* pp = (const int4*)pairs;
    int4 i01 = pp[2 * q];
    int4 i23 = pp[2 * q + 1];
    const ushort_t* zl = z16 + l * 4;
    ushort4 a0 = *(const ushort4*)(zl + (long long)i01.x * 32);
    ushort4 b0 = *(const ushort4*)(zl + (long long)i01.y * 32);
    ushort4 a1 = *(const ushort4*)(zl + (long long)i01.z * 32);
    ushort4 b1 = *(const ushort4*)(zl + (long long)i01.w * 32);
    ushort4 a2 = *(const ushort4*)(zl + (long long)i23.x * 32);
    ushort4 b2 = *(const ushort4*)(zl + (long long)i23.y * 32);
    ushort4 a3 = *(const ushort4*)(zl + (long long)i23.z * 32);
    ushort4 b3 = *(const ushort4*)(zl + (long long)i23.w * 32);
    float d0 = bf2f(a0.x) * bf2f(b0.x) + bf2f(a0.y) * bf2f(b0.y)
             + bf2f(a0.z) * bf2f(b0.z) + bf2f(a0.w) * bf2f(b0.w);
    float d1 = bf2f(a1.x) * bf2f(b1.x) + bf2f(a1.y) * bf2f(b1.y)
             + bf2f(a1.z) * bf2f(b1.z) + bf2f(a1.w) * bf2f(b1.w);
    float d2 = bf2f(a2.x) * bf2f(b2.x) + bf2f(a2.y) * bf2f(b2.y)
             + bf2f(a2.z) * bf2f(b2.z) + bf2f(a2.w) * bf2f(b2.w);
    float d3 = bf2f(a3.x) * bf2f(b3.x) + bf2f(a3.y) * bf2f(b3.y)
             + bf2f(a3.z) * bf2f(b3.z) + bf2f(a3.w) * bf2f(b3.w);
#pragma unroll
    for (int off = 4; off >= 1; off >>= 1) {
        d0 += __shfl_xor(d0, off, 8);
        d1 += __shfl_xor(d1, off, 8);
        d2 += __shfl_xor(d2, off, 8);
        d3 += __shfl_xor(d3, off, 8);
    }
    if (l < 4) {
        float v = (l == 0) ? d0 : (l == 1) ? d1 : (l == 2) ? d2 : d3;
        out[4 * q + l] = v;
    }
}

// ---------------------------------------------------------------------------
extern "C" void kernel_launch(void* const* d_in, const int* in_sizes, int n_in,
                              void* d_out, int out_size, void* d_ws, size_t ws_size,
                              hipStream_t stream) {
    const float* x   = (const float*)d_in[0];
    const int*   ei  = (const int*)d_in[1];   // [2, E] row-major
    const int*   prs = (const int*)d_in[2];   // [P, 2] row-major
    const float* Wl1 = (const float*)d_in[3];
    const float* Wr1 = (const float*)d_in[4];
    const float* b1  = (const float*)d_in[5];
    const float* Wl2 = (const float*)d_in[6];
    const float* Wr2 = (const float*)d_in[7];
    const float* b2  = (const float*)d_in[8];
    float* out = (float*)d_out;

    const int* src = ei;
    const int* dst = ei + N_EDGES;

    // ws (~27 MB): x16 [N*32 us] | h16 [N*32 us] | z16 [N*32 us] | csr [E i]
    //              | deg [N] | incl [N] | offsets [N+1] | bsum [128] | bcursor [256]
    // bed (E ints, 6.4MB) aliases z16 (6.4MB): bed fully consumed by ffill
    // before layer 2 writes z16 (fixed stream order, safe under graph replay).
    ushort_t* x16 = (ushort_t*)d_ws;
    ushort_t* h16 = x16 + (size_t)N_NODES * 32;
    ushort_t* z16 = h16 + (size_t)N_NODES * 32;
    int* csr     = (int*)(z16 + (size_t)N_NODES * 32);
    int* deg     = csr + N_EDGES;
    int* incl    = deg + N_NODES;
    int* offsets = incl + N_NODES;
    int* bsum    = offsets + (N_NODES + 1);
    int* bcursor = bsum + 128;
    int* bed     = (int*)z16;

    const int BT = 256;
    int cvt_blocks  = (N_NODES * 8 + BT - 1) / BT;
    int edge_blocks = (N_EDGES + BT - 1) / BT;
    int node_blocks = (N_NODES + BT - 1) / BT;
    int bsc_blocks  = (N_EDGES + EPB - 1) / EPB;   // 391
    int agg_blocks  = (N_NODES + 7) / 8;           // 12500
    int pair_blocks = (int)(((long long)N_PAIRS * 2 + BT - 1) / BT);

    // ---- CSR build + bf16 staging of x ----
    hipMemsetAsync(deg, 0, sizeof(int) * N_NODES, stream);
    cvt_kernel<<<cvt_blocks, BT, 0, stream>>>(x, x16);
    degree_kernel<<<edge_blocks, BT, 0, stream>>>(dst, deg);
    scan1_kernel<<<NB_SCAN, BT, 0, stream>>>(deg, incl, bsum);
    scan2_kernel<<<1, 64, 0, stream>>>(bsum, offsets);
    scan3_kernel<<<node_blocks, BT, 0, stream>>>(incl, deg, bsum, offsets, bcursor);
    bscatter_kernel<<<bsc_blocks, SC_T, 0, stream>>>(src, dst, bcursor, bed);
    ffill_kernel<<<NBUCKET, SC_T, 0, stream>>>(bed, offsets, csr);

    // ---- layer 1: x16 -> h16 (root from f32 x) ----
    agg_linear_kernel<true, false><<<agg_blocks, BT, 0, stream>>>(
        x16, x, csr, offsets, Wl1, Wr1, b1, h16);
    // ---- layer 2: h16 -> z16 (root from h16; z16 overwrites dead bed) ----
    agg_linear_kernel<false, true><<<agg_blocks, BT, 0, stream>>>(
        h16, nullptr, csr, offsets, Wl2, Wr2, b2, z16);

    // ---- pair scoring from bf16 z ----
    pair_kernel<<<pair_blocks, BT, 0, stream>>>(z16, prs, out);
}